// Round 3
// baseline (3578.163 us; speedup 1.0000x reference)
//
#include <hip/hip_runtime.h>
#include <hip/hip_bf16.h>
#include <stdint.h>

#define NN 200000
#define DD 128

typedef __attribute__((ext_vector_type(8))) short short8;
typedef __attribute__((ext_vector_type(4))) float floatx4;

#define MFMA16(a,b,c) __builtin_amdgcn_mfma_f32_16x16x32_bf16(a,b,c,0,0,0)
#define LGKM_BARRIER() asm volatile("s_waitcnt lgkmcnt(0)\n\ts_barrier" ::: "memory")

// ---- workspace layout (bytes) ----
static constexpr size_t WS_SUM    = 0;        // 8 replicas x 128 f32
static constexpr size_t WS_SQ     = 4096;     // 8 replicas x 128 f32
static constexpr size_t WS_FLAG   = 8192;     // u32
static constexpr size_t WS_HIST   = 8256;     // 13 u32
static constexpr size_t WS_OFF    = 8384;     // 13 u32
static constexpr size_t WS_WHH    = 16384;    // 49152 u16, chunked frag layout
static constexpr size_t WS_WIH    = 114688;   // 49152 u16
static constexpr size_t WS_WSELF  = 212992;   // 16384 u16
static constexpr size_t WS_WNEIGH = 245760;   // 16384 u16
static constexpr size_t WS_DEG    = 278528;   // N u8
static constexpr size_t WS_PERM   = 478528;   // N i32
static constexpr size_t WS_XB     = 1278528;  // N*128 u16 (bf16 x)
// end = 52,478,528 bytes

__device__ __forceinline__ uint16_t f2b(float f){
    uint32_t u = __builtin_bit_cast(uint32_t, f);
    uint32_t r = u + 0x7FFFu + ((u >> 16) & 1u);
    return (uint16_t)(r >> 16);
}
__device__ __forceinline__ float b2f(uint16_t h){
    uint32_t u = ((uint32_t)h) << 16;
    return __builtin_bit_cast(float, u);
}
__device__ __forceinline__ float sigm(float x){
    float e = __builtin_amdgcn_exp2f(x * -1.4426950408889634f);
    return __builtin_amdgcn_rcpf(1.0f + e);
}
__device__ __forceinline__ float tanh_(float x){
    float e = __builtin_amdgcn_exp2f(x * 2.8853900817779268f); // e^{2x}
    return 1.0f - 2.0f * __builtin_amdgcn_rcpf(1.0f + e);
}

// ---- K0: zero BN accumulators + flag + hist + off ----
__global__ void k_init(float* __restrict__ ws){
#pragma unroll
    for (int k = 0; k < 9; k++) ws[threadIdx.x + k * 256] = 0.0f;  // 9216 B
}

// ---- K1: detect mask element size (1-byte bool vs int32) ----
__global__ void k_detect(const uint32_t* __restrict__ mask_w, uint32_t* __restrict__ flag){
    __shared__ uint32_t any;
    if (threadIdx.x == 0) any = 0;
    __syncthreads();
    uint32_t loc = 0;
    for (int i = threadIdx.x; i < 4096; i += 256) loc |= (mask_w[i] & 0xFFFFFF00u);
    if (loc) atomicOr(&any, 1u);
    __syncthreads();
    if (threadIdx.x == 0) *flag = (any != 0) ? 1u : 0u;
}

// ---- K2: BN column stats, float4 loads, 8-replica atomics ----
__global__ void k_stats(const float* __restrict__ feat, float* __restrict__ wsum, float* __restrict__ wsq){
    __shared__ float rs_[256][5], rq_[256][5];   // +1 pad: conflict-free column reduce
    const int cg = threadIdx.x & 31, rr = threadIdx.x >> 5;
    float s0=0,s1=0,s2=0,s3=0,q0=0,q1=0,q2=0,q3=0;
    const float4* f4 = (const float4*)feat;
    for (int r = blockIdx.x * 8 + rr; r < NN; r += gridDim.x * 8){
        float4 v = f4[(size_t)r * 32 + cg];
        s0+=v.x; s1+=v.y; s2+=v.z; s3+=v.w;
        q0+=v.x*v.x; q1+=v.y*v.y; q2+=v.z*v.z; q3+=v.w*v.w;
    }
    rs_[threadIdx.x][0]=s0; rs_[threadIdx.x][1]=s1; rs_[threadIdx.x][2]=s2; rs_[threadIdx.x][3]=s3;
    rq_[threadIdx.x][0]=q0; rq_[threadIdx.x][1]=q1; rq_[threadIdx.x][2]=q2; rq_[threadIdx.x][3]=q3;
    __syncthreads();
    if (threadIdx.x < 32){
        const int rep = (blockIdx.x & 7) * 128;
#pragma unroll
        for (int k = 0; k < 4; k++){
            float a = 0.f, b = 0.f;
#pragma unroll
            for (int r = 0; r < 8; r++){ a += rs_[r*32+threadIdx.x][k]; b += rq_[r*32+threadIdx.x][k]; }
            atomicAdd(&wsum[rep + threadIdx.x*4 + k], a);
            atomicAdd(&wsq [rep + threadIdx.x*4 + k], b);
        }
    }
}

// ---- K3: weights -> bf16 in MFMA-B-fragment-chunked layout ----
__global__ void k_prep(const float* __restrict__ Wih, const float* __restrict__ Whh,
                       const float* __restrict__ Wself, const float* __restrict__ Wneigh,
                       uint16_t* __restrict__ whh_c, uint16_t* __restrict__ wih_c,
                       uint16_t* __restrict__ wself_c, uint16_t* __restrict__ wneigh_c){
    int i = blockIdx.x * 256 + threadIdx.x;
    if (i < 49152){
        int j = i & 7, cidx = i >> 3, n = cidx % 384, kq = cidx / 384;
        whh_c[i] = f2b(Whh[n * 128 + kq * 8 + j]);
    } else if (i < 98304){
        int e = i - 49152;
        int j = e & 7, cidx = e >> 3, n = cidx % 384, kq = cidx / 384;
        wih_c[e] = f2b(Wih[n * 128 + kq * 8 + j]);
    } else if (i < 114688){
        int e = i - 98304;
        int j = e & 7, cidx = e >> 3, n = cidx & 127, kq = cidx >> 7;
        wself_c[e] = f2b(Wself[n * 128 + kq * 8 + j]);
    } else {
        int e = i - 114688;
        int j = e & 7, cidx = e >> 3, n = cidx & 127, kq = cidx >> 7;
        wneigh_c[e] = f2b(Wneigh[n * 128 + kq * 8 + j]);
    }
}

// ---- K4: per-node degree + histogram (LDS-aggregated) ----
__global__ void k_hist(const void* __restrict__ mask, const uint32_t* __restrict__ flag,
                       uint8_t* __restrict__ deg, uint32_t* __restrict__ hist){
    __shared__ uint32_t lh[13];
    if (threadIdx.x < 13) lh[threadIdx.x] = 0;
    __syncthreads();
    const uint32_t flg = *flag;
    for (int n = blockIdx.x * 256 + threadIdx.x; n < NN; n += gridDim.x * 256){
        int d = 0;
        if (flg){
            const uint8_t* m = (const uint8_t*)mask + (size_t)n * 12;
            for (int t = 0; t < 12; t++) d += m[t] ? 1 : 0;
        } else {
            const int* m = (const int*)mask + (size_t)n * 12;
            for (int t = 0; t < 12; t++) d += m[t] ? 1 : 0;
        }
        deg[n] = (uint8_t)d;
        atomicAdd(&lh[d], 1u);
    }
    __syncthreads();
    if (threadIdx.x < 13 && lh[threadIdx.x]) atomicAdd(&hist[threadIdx.x], lh[threadIdx.x]);
}

// ---- K5: bucket offsets (descending degree) ----
__global__ void k_scan(const uint32_t* __restrict__ hist, uint32_t* __restrict__ off){
    if (threadIdx.x == 0){
        uint32_t acc = 0;
        for (int d = 12; d >= 0; d--){ off[d] = acc; acc += hist[d]; }
    }
}

// ---- K6: scatter node ids into perm, block-aggregated atomics ----
__global__ void k_scatter(const uint8_t* __restrict__ deg, uint32_t* __restrict__ off,
                          int* __restrict__ perm){
    __shared__ uint32_t lh[13], basebuf[13];
    if (threadIdx.x < 13) lh[threadIdx.x] = 0;
    __syncthreads();
    int n = blockIdx.x * 256 + threadIdx.x;
    int d = 0; uint32_t r = 0;
    bool valid = n < NN;
    if (valid){ d = deg[n]; r = atomicAdd(&lh[d], 1u); }
    __syncthreads();
    if (threadIdx.x < 13 && lh[threadIdx.x]) basebuf[threadIdx.x] = atomicAdd(&off[threadIdx.x], lh[threadIdx.x]);
    __syncthreads();
    if (valid) perm[basebuf[d] + r] = n;
}

// ---- K7: BN apply -> x bf16 (float4 in / short8 out) ----
__global__ void k_bn(const float* __restrict__ feat, const float* __restrict__ gamma,
                     const float* __restrict__ beta, const float* __restrict__ wsum,
                     const float* __restrict__ wsq, uint16_t* __restrict__ xb){
    const int c8 = (threadIdx.x & 15) * 8;
    const int rr = threadIdx.x >> 4;      // 16 rows per block-iter
    float g[8], b[8];
#pragma unroll
    for (int k = 0; k < 8; k++){
        int col = c8 + k;
        float su = 0.f, sq = 0.f;
#pragma unroll
        for (int r = 0; r < 8; r++){ su += wsum[r*128+col]; sq += wsq[r*128+col]; }
        float mu  = su * (1.0f / NN);
        float var = sq * (1.0f / NN) - mu * mu;
        float rs  = rsqrtf(var + 1e-5f);
        float gg  = gamma[col] * rs;
        g[k] = gg; b[k] = beta[col] - mu * gg;
    }
    for (int r = blockIdx.x * 16 + rr; r < NN; r += gridDim.x * 16){
        const float4* f4 = (const float4*)(feat + (size_t)r * 128 + c8);
        float4 v0 = f4[0], v1 = f4[1];
        short8 o;
        o[0]=(short)f2b(v0.x*g[0]+b[0]); o[1]=(short)f2b(v0.y*g[1]+b[1]);
        o[2]=(short)f2b(v0.z*g[2]+b[2]); o[3]=(short)f2b(v0.w*g[3]+b[3]);
        o[4]=(short)f2b(v1.x*g[4]+b[4]); o[5]=(short)f2b(v1.y*g[5]+b[5]);
        o[6]=(short)f2b(v1.z*g[6]+b[6]); o[7]=(short)f2b(v1.w*g[7]+b[7]);
        *(short8*)(xb + (size_t)r * 128 + c8) = o;
    }
}

// ---- K8: monolithic fused GRU scan, occupancy-first ----
// 4 waves/block (256 thr), 64 rows/block, each wave owns 32 cols of each gate.
// LDS 38.9 KB => 4 blocks/CU resident; launch_bounds(256,4) caps VGPR at 512
// so the ~390-reg working set (192 B-frags + 64 Ax + 32 hC + transients) fits
// without spills. 4 phase-independent waves/SIMD hide the per-step latency
// chain (R2 post-mortem: same-block waves are barrier-locked to the same
// phase; cross-block waves are not — R0's 2-block residency beat R1/R2).
// gi = x_src @ W_ih^T computed fully in-register (no LDS ring).
__global__ __launch_bounds__(256, 4) void k_gru(
    const uint16_t* __restrict__ xb,
    const uint16_t* __restrict__ whh_c, const uint16_t* __restrict__ wih_c,
    const uint16_t* __restrict__ wself_c, const uint16_t* __restrict__ wneigh_c,
    const float* __restrict__ b_ih, const float* __restrict__ b_hh,
    const int* __restrict__ src_idx, const void* __restrict__ mask,
    const uint32_t* __restrict__ flag, const int* __restrict__ perm,
    const uint8_t* __restrict__ degp, float* __restrict__ out)
{
    __shared__ __align__(16) uint16_t hbuf[2][64][136];  // 34816 B
    __shared__ int src_s[768];
    __shared__ uint8_t mask_s[768];
    __shared__ int perm_s[64];
    __shared__ int tmax_s;

    const int tid = threadIdx.x, lane = tid & 63, w = tid >> 6, q = lane >> 4, c = lane & 15;
    const int base = blockIdx.x * 64;

    if (tid < 64) perm_s[tid] = perm[base + tid];
    if (tid == 0) tmax_s = 0;
    __syncthreads();

    const uint32_t flg = *flag;
    for (int i = tid; i < 768; i += 256){
        int node = perm_s[i / 12];
        size_t offn = (size_t)node * 12 + (i % 12);
        src_s[i] = src_idx[offn];
        uint8_t mv;
        if (flg) mv = ((const uint8_t*)mask)[offn] ? 1 : 0;
        else     mv = ((const int*)mask)[offn] ? 1 : 0;
        mask_s[i] = mv;
    }
    if (tid < 64) atomicMax(&tmax_s, (int)degp[perm_s[tid]]);
    for (int i = tid; i < 64 * 136 * 2 / 2; i += 256) ((uint32_t*)hbuf[0])[i] = 0;

    // persistent B frags for BOTH W_ih and W_hh; wave owns cols
    // n = g*128 + w*32 + dg*16 + c  (dg in {0,1})
    short8 Bi[3][2][4], Bh[3][2][4];
    float bsum[2][2], bi2[2], bh2[2];   // bsum[g<2][dg] = b_ih+b_hh
#pragma unroll
    for (int g = 0; g < 3; g++)
#pragma unroll
        for (int dg = 0; dg < 2; dg++){
            const int n = g * 128 + w * 32 + dg * 16 + c;
#pragma unroll
            for (int kb = 0; kb < 4; kb++){
                Bi[g][dg][kb] = *(const short8*)(wih_c + ((size_t)(kb * 4 + q) * 384 + n) * 8);
                Bh[g][dg][kb] = *(const short8*)(whh_c + ((size_t)(kb * 4 + q) * 384 + n) * 8);
            }
            float vi = b_ih[n], vh = b_hh[n];
            if (g < 2) bsum[g][dg] = vi + vh;
            else { bi2[dg] = vi; bh2[dg] = vh; }
        }

    float hC[4][2][4];
#pragma unroll
    for (int m = 0; m < 4; m++)
#pragma unroll
        for (int dg = 0; dg < 2; dg++)
#pragma unroll
            for (int j = 0; j < 4; j++) hC[m][dg][j] = 0.f;

    __syncthreads();
    const int tmax = tmax_s;

    if (tmax > 0){
        short8 Ax[4][4];
        // prefetch Ax for t=0 (A-frag rows = m*16 + c -> gathered source rows)
#pragma unroll
        for (int m = 0; m < 4; m++){
            int s = src_s[(m * 16 + c) * 12];
            const uint16_t* a = xb + (size_t)s * 128 + q * 8;
#pragma unroll
            for (int kb = 0; kb < 4; kb++) Ax[m][kb] = *(const short8*)(a + kb * 32);
        }
        for (int t = 0; t < tmax; t++){
            const int rb = t & 1, wbuf = rb ^ 1;
            const int tn = (t + 1 < tmax) ? t + 1 : t;
#pragma unroll
            for (int m = 0; m < 4; m++){
                short8 Ah[4];
#pragma unroll
                for (int kb = 0; kb < 4; kb++)
                    Ah[kb] = *(const short8*)&hbuf[rb][m * 16 + c][kb * 32 + q * 8];
                floatx4 ah[3][2], ax[3][2];
#pragma unroll
                for (int g = 0; g < 3; g++)
#pragma unroll
                    for (int dg = 0; dg < 2; dg++){
                        floatx4 h0 = {0.f, 0.f, 0.f, 0.f}, x0 = {0.f, 0.f, 0.f, 0.f};
#pragma unroll
                        for (int kb = 0; kb < 4; kb++){
                            h0 = MFMA16(Ah[kb],    Bh[g][dg][kb], h0);
                            x0 = MFMA16(Ax[m][kb], Bi[g][dg][kb], x0);
                        }
                        ah[g][dg] = h0; ax[g][dg] = x0;
                    }
                // reload Ax[m] for step t+1 (in flight across the barrier)
                {
                    int s = src_s[(m * 16 + c) * 12 + tn];
                    const uint16_t* a = xb + (size_t)s * 128 + q * 8;
#pragma unroll
                    for (int kb = 0; kb < 4; kb++) Ax[m][kb] = *(const short8*)(a + kb * 32);
                }
                // gate math (C layout: row = m*16 + q*4 + j, col = w*32 + dg*16 + c)
#pragma unroll
                for (int dg = 0; dg < 2; dg++)
#pragma unroll
                    for (int j = 0; j < 4; j++){
                        uint8_t mk = mask_s[(m * 16 + q * 4 + j) * 12 + t];
                        float r  = sigm(ax[0][dg][j] + ah[0][dg][j] + bsum[0][dg]);
                        float z  = sigm(ax[1][dg][j] + ah[1][dg][j] + bsum[1][dg]);
                        float hn = ah[2][dg][j] + bh2[dg];
                        float nn = tanh_(ax[2][dg][j] + bi2[dg] + r * hn);
                        float hold = hC[m][dg][j];
                        float hnew = nn + z * (hold - nn);
                        hnew = mk ? hnew : hold;
                        hC[m][dg][j] = hnew;
                        hbuf[wbuf][m * 16 + q * 4 + j][w * 32 + dg * 16 + c] = f2b(hnew);
                    }
            }
            // barrier without vmcnt drain: LDS (lgkm) must be visible; the Ax
            // prefetch (vm, register dest, read-only src) may stay outstanding.
            LGKM_BARRIER();
        }
    }

    const int fb = tmax & 1;   // final h buffer

    // epilogue: out = x @ W_self^T + h @ W_neigh^T  (32 cols per wave)
    floatx4 acc2[4][2];
#pragma unroll
    for (int m = 0; m < 4; m++)
#pragma unroll
        for (int dg = 0; dg < 2; dg++) acc2[m][dg] = floatx4{0.f, 0.f, 0.f, 0.f};
    short8 Bs_[2][4], Bn_[2][4];
#pragma unroll
    for (int dg = 0; dg < 2; dg++)
#pragma unroll
        for (int kb = 0; kb < 4; kb++){
            Bs_[dg][kb] = *(const short8*)(wself_c  + ((size_t)(kb * 4 + q) * 128 + w * 32 + dg * 16 + c) * 8);
            Bn_[dg][kb] = *(const short8*)(wneigh_c + ((size_t)(kb * 4 + q) * 128 + w * 32 + dg * 16 + c) * 8);
        }
#pragma unroll
    for (int m = 0; m < 4; m++){
        short8 A[4];
#pragma unroll
        for (int kb = 0; kb < 4; kb++)
            A[kb] = *(const short8*)&hbuf[fb][m * 16 + c][kb * 32 + q * 8];
#pragma unroll
        for (int dg = 0; dg < 2; dg++)
#pragma unroll
            for (int kb = 0; kb < 4; kb++) acc2[m][dg] = MFMA16(A[kb], Bn_[dg][kb], acc2[m][dg]);
        int xrow = perm_s[m * 16 + c];
        const uint16_t* a = xb + (size_t)xrow * 128 + q * 8;
#pragma unroll
        for (int kb = 0; kb < 4; kb++) A[kb] = *(const short8*)(a + kb * 32);
#pragma unroll
        for (int dg = 0; dg < 2; dg++)
#pragma unroll
            for (int kb = 0; kb < 4; kb++) acc2[m][dg] = MFMA16(A[kb], Bs_[dg][kb], acc2[m][dg]);
    }
#pragma unroll
    for (int m = 0; m < 4; m++){
#pragma unroll
        for (int j = 0; j < 4; j++){
            int orow = perm_s[m * 16 + q * 4 + j];
#pragma unroll
            for (int dg = 0; dg < 2; dg++)
                out[(size_t)orow * 128 + w * 32 + dg * 16 + c] = acc2[m][dg][j];
        }
    }
}

extern "C" void kernel_launch(void* const* d_in, const int* in_sizes, int n_in,
                              void* d_out, int out_size, void* d_ws, size_t ws_size,
                              hipStream_t stream) {
    const float* feat    = (const float*)d_in[0];
    const float* gamma   = (const float*)d_in[1];
    const float* beta    = (const float*)d_in[2];
    const float* W_ih    = (const float*)d_in[3];
    const float* W_hh    = (const float*)d_in[4];
    const float* b_ih    = (const float*)d_in[5];
    const float* b_hh    = (const float*)d_in[6];
    const float* W_self  = (const float*)d_in[7];
    const float* W_neigh = (const float*)d_in[8];
    const int*   src_idx = (const int*)d_in[9];
    const void*  mask    = (const void*)d_in[10];
    float* out = (float*)d_out;

    char* ws = (char*)d_ws;
    float*    wsum     = (float*)(ws + WS_SUM);
    float*    wsq      = (float*)(ws + WS_SQ);
    uint32_t* flag     = (uint32_t*)(ws + WS_FLAG);
    uint32_t* hist     = (uint32_t*)(ws + WS_HIST);
    uint32_t* off      = (uint32_t*)(ws + WS_OFF);
    uint16_t* whh_c    = (uint16_t*)(ws + WS_WHH);
    uint16_t* wih_c    = (uint16_t*)(ws + WS_WIH);
    uint16_t* wself_c  = (uint16_t*)(ws + WS_WSELF);
    uint16_t* wneigh_c = (uint16_t*)(ws + WS_WNEIGH);
    uint8_t*  deg      = (uint8_t*)(ws + WS_DEG);
    int*      perm     = (int*)(ws + WS_PERM);
    uint16_t* xb       = (uint16_t*)(ws + WS_XB);

    k_init   <<<1,    256, 0, stream>>>((float*)ws);
    k_detect <<<1,    256, 0, stream>>>((const uint32_t*)mask, flag);
    k_stats  <<<512,  256, 0, stream>>>(feat, wsum, wsq);
    k_prep   <<<512,  256, 0, stream>>>(W_ih, W_hh, W_self, W_neigh, whh_c, wih_c, wself_c, wneigh_c);
    k_hist   <<<256,  256, 0, stream>>>(mask, flag, deg, hist);
    k_scan   <<<1,    64,  0, stream>>>(hist, off);
    k_scatter<<<782,  256, 0, stream>>>(deg, off, perm);
    k_bn     <<<782,  256, 0, stream>>>(feat, gamma, beta, wsum, wsq, xb);
    k_gru    <<<3125, 256, 0, stream>>>(xb, whh_c, wih_c, wself_c, wneigh_c, b_ih, b_hh,
                                        src_idx, mask, flag, perm, deg, out);
}

// Round 6
// 676.322 us; speedup vs baseline: 5.2906x; 5.2906x over previous
//
#include <hip/hip_runtime.h>
#include <hip/hip_bf16.h>
#include <stdint.h>

#define NN 200000
#define DD 128
#define PERM_PAD 200064   // 1563 blocks * 128 rows

typedef __attribute__((ext_vector_type(8))) short short8;
typedef __attribute__((ext_vector_type(4))) float floatx4;

#define MFMA16(a,b,c) __builtin_amdgcn_mfma_f32_16x16x32_bf16(a,b,c,0,0,0)
#define LGKM_BARRIER() asm volatile("s_waitcnt lgkmcnt(0)\n\ts_barrier" ::: "memory")

// ---- workspace layout (bytes) ----
static constexpr size_t WS_SUM    = 0;        // 8 replicas x 128 f32
static constexpr size_t WS_SQ     = 4096;     // 8 replicas x 128 f32
static constexpr size_t WS_FLAG   = 8192;     // u32
static constexpr size_t WS_HIST   = 8256;     // 13 u32
static constexpr size_t WS_OFF    = 8384;     // 13 u32
static constexpr size_t WS_WHH    = 16384;    // 49152 u16, chunked frag layout
static constexpr size_t WS_WIH    = 114688;   // 49152 u16
static constexpr size_t WS_WSELF  = 212992;   // 16384 u16
static constexpr size_t WS_WNEIGH = 245760;   // 16384 u16
static constexpr size_t WS_DEG    = 278528;   // N u8
static constexpr size_t WS_PERM   = 478528;   // PERM_PAD i32 (padded)
static constexpr size_t WS_XB     = 1478528;  // N*128 u16 (bf16 x)
// end = 52,678,528 bytes

__device__ __forceinline__ uint16_t f2b(float f){
    uint32_t u = __builtin_bit_cast(uint32_t, f);
    uint32_t r = u + 0x7FFFu + ((u >> 16) & 1u);
    return (uint16_t)(r >> 16);
}
__device__ __forceinline__ float b2f(uint16_t h){
    uint32_t u = ((uint32_t)h) << 16;
    return __builtin_bit_cast(float, u);
}
__device__ __forceinline__ float sigm(float x){
    float e = __builtin_amdgcn_exp2f(x * -1.4426950408889634f);
    return __builtin_amdgcn_rcpf(1.0f + e);
}
__device__ __forceinline__ float tanh_(float x){
    float e = __builtin_amdgcn_exp2f(x * 2.8853900817779268f); // e^{2x}
    return 1.0f - 2.0f * __builtin_amdgcn_rcpf(1.0f + e);
}

// ---- K0: zero BN accumulators + flag + hist + off ----
__global__ void k_init(float* __restrict__ ws){
#pragma unroll
    for (int k = 0; k < 9; k++) ws[threadIdx.x + k * 256] = 0.0f;  // 9216 B
}

// ---- K1: detect mask element size (1-byte bool vs int32) ----
__global__ void k_detect(const uint32_t* __restrict__ mask_w, uint32_t* __restrict__ flag){
    __shared__ uint32_t any;
    if (threadIdx.x == 0) any = 0;
    __syncthreads();
    uint32_t loc = 0;
    for (int i = threadIdx.x; i < 4096; i += 256) loc |= (mask_w[i] & 0xFFFFFF00u);
    if (loc) atomicOr(&any, 1u);
    __syncthreads();
    if (threadIdx.x == 0) *flag = (any != 0) ? 1u : 0u;
}

// ---- K2: BN column stats, float4 loads, 8-replica atomics ----
__global__ void k_stats(const float* __restrict__ feat, float* __restrict__ wsum, float* __restrict__ wsq){
    __shared__ float rs_[256][5], rq_[256][5];   // +1 pad: conflict-free column reduce
    const int cg = threadIdx.x & 31, rr = threadIdx.x >> 5;
    float s0=0,s1=0,s2=0,s3=0,q0=0,q1=0,q2=0,q3=0;
    const float4* f4 = (const float4*)feat;
    for (int r = blockIdx.x * 8 + rr; r < NN; r += gridDim.x * 8){
        float4 v = f4[(size_t)r * 32 + cg];
        s0+=v.x; s1+=v.y; s2+=v.z; s3+=v.w;
        q0+=v.x*v.x; q1+=v.y*v.y; q2+=v.z*v.z; q3+=v.w*v.w;
    }
    rs_[threadIdx.x][0]=s0; rs_[threadIdx.x][1]=s1; rs_[threadIdx.x][2]=s2; rs_[threadIdx.x][3]=s3;
    rq_[threadIdx.x][0]=q0; rq_[threadIdx.x][1]=q1; rq_[threadIdx.x][2]=q2; rq_[threadIdx.x][3]=q3;
    __syncthreads();
    if (threadIdx.x < 32){
        const int rep = (blockIdx.x & 7) * 128;
#pragma unroll
        for (int k = 0; k < 4; k++){
            float a = 0.f, b = 0.f;
#pragma unroll
            for (int r = 0; r < 8; r++){ a += rs_[r*32+threadIdx.x][k]; b += rq_[r*32+threadIdx.x][k]; }
            atomicAdd(&wsum[rep + threadIdx.x*4 + k], a);
            atomicAdd(&wsq [rep + threadIdx.x*4 + k], b);
        }
    }
}

// ---- K3: weights -> bf16 in MFMA-B-fragment-chunked layout ----
__global__ void k_prep(const float* __restrict__ Wih, const float* __restrict__ Whh,
                       const float* __restrict__ Wself, const float* __restrict__ Wneigh,
                       uint16_t* __restrict__ whh_c, uint16_t* __restrict__ wih_c,
                       uint16_t* __restrict__ wself_c, uint16_t* __restrict__ wneigh_c){
    int i = blockIdx.x * 256 + threadIdx.x;
    if (i < 49152){
        int j = i & 7, cidx = i >> 3, n = cidx % 384, kq = cidx / 384;
        whh_c[i] = f2b(Whh[n * 128 + kq * 8 + j]);
    } else if (i < 98304){
        int e = i - 49152;
        int j = e & 7, cidx = e >> 3, n = cidx % 384, kq = cidx / 384;
        wih_c[e] = f2b(Wih[n * 128 + kq * 8 + j]);
    } else if (i < 114688){
        int e = i - 98304;
        int j = e & 7, cidx = e >> 3, n = cidx & 127, kq = cidx >> 7;
        wself_c[e] = f2b(Wself[n * 128 + kq * 8 + j]);
    } else {
        int e = i - 114688;
        int j = e & 7, cidx = e >> 3, n = cidx & 127, kq = cidx >> 7;
        wneigh_c[e] = f2b(Wneigh[n * 128 + kq * 8 + j]);
    }
}

// ---- K4: per-node degree + histogram (LDS-aggregated) ----
__global__ void k_hist(const void* __restrict__ mask, const uint32_t* __restrict__ flag,
                       uint8_t* __restrict__ deg, uint32_t* __restrict__ hist){
    __shared__ uint32_t lh[13];
    if (threadIdx.x < 13) lh[threadIdx.x] = 0;
    __syncthreads();
    const uint32_t flg = *flag;
    for (int n = blockIdx.x * 256 + threadIdx.x; n < NN; n += gridDim.x * 256){
        int d = 0;
        if (flg){
            const uint8_t* m = (const uint8_t*)mask + (size_t)n * 12;
            for (int t = 0; t < 12; t++) d += m[t] ? 1 : 0;
        } else {
            const int* m = (const int*)mask + (size_t)n * 12;
            for (int t = 0; t < 12; t++) d += m[t] ? 1 : 0;
        }
        deg[n] = (uint8_t)d;
        atomicAdd(&lh[d], 1u);
    }
    __syncthreads();
    if (threadIdx.x < 13 && lh[threadIdx.x]) atomicAdd(&hist[threadIdx.x], lh[threadIdx.x]);
}

// ---- K5: bucket offsets (descending degree) ----
__global__ void k_scan(const uint32_t* __restrict__ hist, uint32_t* __restrict__ off){
    if (threadIdx.x == 0){
        uint32_t acc = 0;
        for (int d = 12; d >= 0; d--){ off[d] = acc; acc += hist[d]; }
    }
}

// ---- K6: scatter node ids into perm, block-aggregated atomics; pad tail ----
__global__ void k_scatter(const uint8_t* __restrict__ deg, uint32_t* __restrict__ off,
                          int* __restrict__ perm){
    __shared__ uint32_t lh[13], basebuf[13];
    if (threadIdx.x < 13) lh[threadIdx.x] = 0;
    __syncthreads();
    int n = blockIdx.x * 256 + threadIdx.x;
    int d = 0; uint32_t r = 0;
    bool valid = n < NN;
    if (valid){ d = deg[n]; r = atomicAdd(&lh[d], 1u); }
    __syncthreads();
    if (threadIdx.x < 13 && lh[threadIdx.x]) basebuf[threadIdx.x] = atomicAdd(&off[threadIdx.x], lh[threadIdx.x]);
    __syncthreads();
    if (valid) perm[basebuf[d] + r] = n;
    else if (n < PERM_PAD) perm[n] = 0;   // tail rows alias node 0 (benign dup)
}

// ---- K7: BN apply -> x bf16 (float4 in / short8 out) ----
__global__ void k_bn(const float* __restrict__ feat, const float* __restrict__ gamma,
                     const float* __restrict__ beta, const float* __restrict__ wsum,
                     const float* __restrict__ wsq, uint16_t* __restrict__ xb){
    const int c8 = (threadIdx.x & 15) * 8;
    const int rr = threadIdx.x >> 4;      // 16 rows per block-iter
    float g[8], b[8];
#pragma unroll
    for (int k = 0; k < 8; k++){
        int col = c8 + k;
        float su = 0.f, sq = 0.f;
#pragma unroll
        for (int r = 0; r < 8; r++){ su += wsum[r*128+col]; sq += wsq[r*128+col]; }
        float mu  = su * (1.0f / NN);
        float var = sq * (1.0f / NN) - mu * mu;
        float rs  = rsqrtf(var + 1e-5f);
        float gg  = gamma[col] * rs;
        g[k] = gg; b[k] = beta[col] - mu * gg;
    }
    for (int r = blockIdx.x * 16 + rr; r < NN; r += gridDim.x * 16){
        const float4* f4 = (const float4*)(feat + (size_t)r * 128 + c8);
        float4 v0 = f4[0], v1 = f4[1];
        short8 o;
        o[0]=(short)f2b(v0.x*g[0]+b[0]); o[1]=(short)f2b(v0.y*g[1]+b[1]);
        o[2]=(short)f2b(v0.z*g[2]+b[2]); o[3]=(short)f2b(v0.w*g[3]+b[3]);
        o[4]=(short)f2b(v1.x*g[4]+b[4]); o[5]=(short)f2b(v1.y*g[5]+b[5]);
        o[6]=(short)f2b(v1.z*g[6]+b[6]); o[7]=(short)f2b(v1.w*g[7]+b[7]);
        *(short8*)(xb + (size_t)r * 128 + c8) = o;
    }
}

// ---- K8: fused GRU scan with block-shared staged x-gather ----
// 128 rows/block, 8 waves (512 thr), wave owns 16 cols of each gate.
// x rows staged ONCE per block per step into xs (reg-staged, loads issued a
// step ahead). BOTH xs and hbuf use the same XOR-chunk swizzle
// (storage_chunk = logical_chunk ^ (row&7), 16B chunks): ds_read_b128 of
// A-frags is 2-way (free) instead of 8-way with the old [136]-pad hbuf.
// R4 bug fixed: hbuf zero-init now covers the WHOLE buffer (was 1/4 -> NaN).
__global__ __launch_bounds__(512, 1) void k_gru(
    const uint16_t* __restrict__ xb,
    const uint16_t* __restrict__ whh_c, const uint16_t* __restrict__ wih_c,
    const uint16_t* __restrict__ wself_c, const uint16_t* __restrict__ wneigh_c,
    const float* __restrict__ b_ih, const float* __restrict__ b_hh,
    const int* __restrict__ src_idx, const void* __restrict__ mask,
    const uint32_t* __restrict__ flag, const int* __restrict__ perm,
    const uint8_t* __restrict__ degp, float* __restrict__ out)
{
    __shared__ __align__(16) uint16_t hbuf[2][128][128];  // 65536 B, swizzled
    __shared__ __align__(16) uint16_t xs[2][128][128];    // 65536 B, swizzled
    __shared__ int src_s[1536];
    __shared__ uint8_t mask_s[1536];
    __shared__ int perm_s[128];
    __shared__ int tmax_s;

    const int tid = threadIdx.x, lane = tid & 63, w = tid >> 6, q = lane >> 4, c = lane & 15;
    const int base = blockIdx.x * 128;

    if (tid < 128) perm_s[tid] = perm[base + tid];
    if (tid == 0) tmax_s = 0;
    __syncthreads();

    const uint32_t flg = *flag;
    for (int i = tid; i < 1536; i += 512){
        int node = perm_s[i / 12];
        size_t offn = (size_t)node * 12 + (i % 12);
        src_s[i] = src_idx[offn];
        uint8_t mv;
        if (flg) mv = ((const uint8_t*)mask)[offn] ? 1 : 0;
        else     mv = ((const int*)mask)[offn] ? 1 : 0;
        mask_s[i] = mv;
    }
    if (tid < 128) atomicMax(&tmax_s, (int)degp[perm_s[tid]]);
    for (int i = tid; i < 16384; i += 512) ((uint32_t*)hbuf)[i] = 0;  // FULL hbuf (both bufs)

    // persistent B frags: cols n = g*128 + w*16 + c, both W_ih and W_hh
    short8 Bi[3][4], Bh[3][4];
    float bs0, bs1, bi2, bh2;
    {
        const int n0 = w * 16 + c;
#pragma unroll
        for (int g = 0; g < 3; g++){
            int n = g * 128 + n0;
#pragma unroll
            for (int kb = 0; kb < 4; kb++){
                Bi[g][kb] = *(const short8*)(wih_c + ((size_t)(kb * 4 + q) * 384 + n) * 8);
                Bh[g][kb] = *(const short8*)(whh_c + ((size_t)(kb * 4 + q) * 384 + n) * 8);
            }
        }
        bs0 = b_ih[n0]       + b_hh[n0];
        bs1 = b_ih[128 + n0] + b_hh[128 + n0];
        bi2 = b_ih[256 + n0];
        bh2 = b_hh[256 + n0];
    }

    float hC[8][4];
#pragma unroll
    for (int m = 0; m < 8; m++)
#pragma unroll
        for (int j = 0; j < 4; j++) hC[m][j] = 0.f;

    __syncthreads();
    const int tmax = tmax_s;

    if (tmax > 0){
        // staging: wave w covers rows w*16 .. w*16+15 (4 instr x 4 rows)
        const int srow = (lane >> 4);          // 0..3 within instr group
        const int pc   = lane & 15;            // 16B chunk index
        short8 sx[4];
        auto stageLoad = [&](int tg){
#pragma unroll
            for (int i = 0; i < 4; i++){
                int r = w * 16 + i * 4 + srow;
                int s = src_s[r * 12 + tg];
                sx[i] = *(const short8*)(xb + (size_t)s * 128 + pc * 8);
            }
        };
        auto stageWrite = [&](int sl){
#pragma unroll
            for (int i = 0; i < 4; i++){
                int r = w * 16 + i * 4 + srow;
                int wc = pc ^ (r & 7);
                *(short8*)&xs[sl][r][wc * 8] = sx[i];
            }
        };
        stageLoad(0);
        stageWrite(0);
        LGKM_BARRIER();
        for (int t = 0; t < tmax; t++){
            const int rb = t & 1, wbuf = rb ^ 1;
            const int tn = (t + 1 < tmax) ? t + 1 : t;
            stageLoad(tn);                         // global loads in flight across compute
#pragma unroll
            for (int m = 0; m < 8; m++){
                const int arow = m * 16 + c;
                short8 Ah[4], Ax[4];
#pragma unroll
                for (int kb = 0; kb < 4; kb++){
                    const int sc = ((kb * 4 + q) ^ (c & 7)) * 8;   // swizzled chunk
                    Ah[kb] = *(const short8*)&hbuf[rb][arow][sc];
                    Ax[kb] = *(const short8*)&xs[rb][arow][sc];
                }
                floatx4 agi[3], agh[3];
#pragma unroll
                for (int g = 0; g < 3; g++){
                    floatx4 x0 = {0.f, 0.f, 0.f, 0.f}, h0 = {0.f, 0.f, 0.f, 0.f};
#pragma unroll
                    for (int kb = 0; kb < 4; kb++){
                        x0 = MFMA16(Ax[kb], Bi[g][kb], x0);
                        h0 = MFMA16(Ah[kb], Bh[g][kb], h0);
                    }
                    agi[g] = x0; agh[g] = h0;
                }
#pragma unroll
                for (int j = 0; j < 4; j++){
                    const int row = m * 16 + q * 4 + j;
                    uint8_t mk = mask_s[row * 12 + t];
                    float r  = sigm(agi[0][j] + agh[0][j] + bs0);
                    float z  = sigm(agi[1][j] + agh[1][j] + bs1);
                    float hn = agh[2][j] + bh2;
                    float nn = tanh_(agi[2][j] + bi2 + r * hn);
                    float hold = hC[m][j];
                    float hnew = nn + z * (hold - nn);
                    hnew = mk ? hnew : hold;
                    hC[m][j] = hnew;
                    // swizzled scalar write: logical chunk = w*2 + (c>>3)
                    hbuf[wbuf][row][(((w * 2 + (c >> 3)) ^ (row & 7)) << 3) + (c & 7)] = f2b(hnew);
                }
            }
            stageWrite(wbuf);                      // xs slot wbuf consumed at t-1, safe
            LGKM_BARRIER();                        // lgkm only; no vm drain needed
        }
    }

    const int fb = tmax & 1;   // final h buffer

    // epilogue: out = x @ W_self^T + h @ W_neigh^T  (16 cols per wave)
    floatx4 acc2[8];
#pragma unroll
    for (int m = 0; m < 8; m++) acc2[m] = floatx4{0.f, 0.f, 0.f, 0.f};
    short8 Bs_[4], Bn_[4];
#pragma unroll
    for (int kb = 0; kb < 4; kb++){
        Bs_[kb] = *(const short8*)(wself_c  + ((size_t)(kb * 4 + q) * 128 + w * 16 + c) * 8);
        Bn_[kb] = *(const short8*)(wneigh_c + ((size_t)(kb * 4 + q) * 128 + w * 16 + c) * 8);
    }
#pragma unroll
    for (int m = 0; m < 8; m++){
        short8 A[4];
#pragma unroll
        for (int kb = 0; kb < 4; kb++)
            A[kb] = *(const short8*)&hbuf[fb][m * 16 + c][((kb * 4 + q) ^ (c & 7)) * 8];
#pragma unroll
        for (int kb = 0; kb < 4; kb++) acc2[m] = MFMA16(A[kb], Bn_[kb], acc2[m]);
        int xrow = perm_s[m * 16 + c];
        const uint16_t* a = xb + (size_t)xrow * 128 + q * 8;
#pragma unroll
        for (int kb = 0; kb < 4; kb++) A[kb] = *(const short8*)(a + kb * 32);
#pragma unroll
        for (int kb = 0; kb < 4; kb++) acc2[m] = MFMA16(A[kb], Bs_[kb], acc2[m]);
    }
#pragma unroll
    for (int m = 0; m < 8; m++){
#pragma unroll
        for (int j = 0; j < 4; j++){
            int orow = perm_s[m * 16 + q * 4 + j];
            out[(size_t)orow * 128 + w * 16 + c] = acc2[m][j];
        }
    }
}

extern "C" void kernel_launch(void* const* d_in, const int* in_sizes, int n_in,
                              void* d_out, int out_size, void* d_ws, size_t ws_size,
                              hipStream_t stream) {
    const float* feat    = (const float*)d_in[0];
    const float* gamma   = (const float*)d_in[1];
    const float* beta    = (const float*)d_in[2];
    const float* W_ih    = (const float*)d_in[3];
    const float* W_hh    = (const float*)d_in[4];
    const float* b_ih    = (const float*)d_in[5];
    const float* b_hh    = (const float*)d_in[6];
    const float* W_self  = (const float*)d_in[7];
    const float* W_neigh = (const float*)d_in[8];
    const int*   src_idx = (const int*)d_in[9];
    const void*  mask    = (const void*)d_in[10];
    float* out = (float*)d_out;

    char* ws = (char*)d_ws;
    float*    wsum     = (float*)(ws + WS_SUM);
    float*    wsq      = (float*)(ws + WS_SQ);
    uint32_t* flag     = (uint32_t*)(ws + WS_FLAG);
    uint32_t* hist     = (uint32_t*)(ws + WS_HIST);
    uint32_t* off      = (uint32_t*)(ws + WS_OFF);
    uint16_t* whh_c    = (uint16_t*)(ws + WS_WHH);
    uint16_t* wih_c    = (uint16_t*)(ws + WS_WIH);
    uint16_t* wself_c  = (uint16_t*)(ws + WS_WSELF);
    uint16_t* wneigh_c = (uint16_t*)(ws + WS_WNEIGH);
    uint8_t*  deg      = (uint8_t*)(ws + WS_DEG);
    int*      perm     = (int*)(ws + WS_PERM);
    uint16_t* xb       = (uint16_t*)(ws + WS_XB);

    k_init   <<<1,    256, 0, stream>>>((float*)ws);
    k_detect <<<1,    256, 0, stream>>>((const uint32_t*)mask, flag);
    k_stats  <<<512,  256, 0, stream>>>(feat, wsum, wsq);
    k_prep   <<<512,  256, 0, stream>>>(W_ih, W_hh, W_self, W_neigh, whh_c, wih_c, wself_c, wneigh_c);
    k_hist   <<<256,  256, 0, stream>>>(mask, flag, deg, hist);
    k_scan   <<<1,    64,  0, stream>>>(hist, off);
    k_scatter<<<782,  256, 0, stream>>>(deg, off, perm);
    k_bn     <<<782,  256, 0, stream>>>(feat, gamma, beta, wsum, wsq, xb);
    k_gru    <<<1563, 512, 0, stream>>>(xb, whh_c, wih_c, wself_c, wneigh_c, b_ih, b_hh,
                                        src_idx, mask, flag, perm, deg, out);
}